// Round 7
// baseline (336.788 us; speedup 1.0000x reference)
//
#include <hip/hip_runtime.h>

#define BATCH 16
#define CIN   256
#define NSP   4096
#define HID   512

typedef short v8s __attribute__((ext_vector_type(8)));
typedef float v4f __attribute__((ext_vector_type(4)));

__device__ __forceinline__ unsigned short f2bf(float f) {
    union { float f; unsigned u; } a; a.f = f;
    unsigned r = a.u + 0x7fffu + ((a.u >> 16) & 1u);
    return (unsigned short)(r >> 16);
}

__device__ __forceinline__ void gld_lds16(const unsigned short* g, unsigned short* l) {
    __builtin_amdgcn_global_load_lds(
        (const __attribute__((address_space(1))) unsigned int*)g,
        (__attribute__((address_space(3))) unsigned int*)l,
        16, 0, 0);
}

// Swizzled 128x64 bf16 LDS tile: slot s (8 shorts) of row r stored at slot (s+r)&7.
// Staging: lane (srow8=lane>>3, sslot=lane&7) loads global col ((sslot-srow8)&7)*8.
// Reader of (row r, k-slot s): LDS col = ((s + r)&7)*8; since s(h=1)=s(h=0)^4 -> addr^32.

// ---------------- P: weights prep + x prep + zacc zero (merged) ---------------------
__global__ __launch_bounds__(256) void k_prep(const float* __restrict__ x,
                                              const float* __restrict__ wq,
                                              unsigned short* __restrict__ xbf,
                                              unsigned short* __restrict__ xT,
                                              unsigned short* __restrict__ wbf,
                                              unsigned short* __restrict__ wqT,
                                              float* __restrict__ zacc) {
    const int bid = blockIdx.x;
    const int t = threadIdx.x;
    if (bid >= 4320) {                        // 32 blocks: zero zacc (16x512 fp32)
        zacc[(bid - 4320) * 256 + t] = 0.f;
        return;
    }
    if (bid >= 4096) {
        const int wid = bid - 4096;
        if (wid < 192) {                      // bf16 convert of full w_qkv
            const int g = wid * 256 + t;
            const float4 f0 = *(const float4*)(wq + (size_t)g * 8);
            const float4 f1 = *(const float4*)(wq + (size_t)g * 8 + 4);
            union { unsigned short s[8]; uint4 u; } p;
            p.s[0] = f2bf(f0.x); p.s[1] = f2bf(f0.y); p.s[2] = f2bf(f0.z); p.s[3] = f2bf(f0.w);
            p.s[4] = f2bf(f1.x); p.s[5] = f2bf(f1.y); p.s[6] = f2bf(f1.z); p.s[7] = f2bf(f1.w);
            *(uint4*)(wbf + (size_t)g * 8) = p.u;
            return;
        }
        __shared__ float tile[64 * 65];       // 32 blocks: wqT transpose (q part)
        const int bb = wid - 192;
        const int u0 = (bb & 7) * 64, c0 = (bb >> 3) * 64;
        {
            const int cl = (t & 15) * 4, ul = t >> 4;
            #pragma unroll
            for (int i = 0; i < 4; i++) {
                int u = ul + i * 16;
                const float4 f = *(const float4*)(wq + (size_t)(u0 + u) * CIN + c0 + cl);
                *(float4*)(&tile[u * 65 + cl]) = f;
            }
        }
        __syncthreads();
        {
            const int ul4 = (t & 15) * 4, cl = t >> 4;
            #pragma unroll
            for (int i = 0; i < 4; i++) {
                int c = cl + i * 16;
                union { unsigned short s[4]; uint2 u; } p;
                #pragma unroll
                for (int j = 0; j < 4; j++)
                    p.s[j] = f2bf(tile[(ul4 + j) * 65 + c]);
                *(uint2*)(wqT + (size_t)(c0 + c) * HID + u0 + ul4) = p.u;
            }
        }
        return;
    }
    // x prep: 4096 blocks of 64x64 tiles
    __shared__ float tile[64 * 65];
    const int n0 = (bid & 63) * 64, c0 = ((bid >> 6) & 3) * 64, bz = bid >> 8;
    const float* xb = x + (size_t)bz * CIN * NSP;
    {
        const int nl = (t & 15) * 4, cl = t >> 4;
        #pragma unroll
        for (int i = 0; i < 4; i++) {
            int c = cl + i * 16;
            const float4 f = *(const float4*)(xb + (size_t)(c0 + c) * NSP + n0 + nl);
            *(float4*)(&tile[c * 65 + nl]) = f;
            union { unsigned short s[4]; uint2 u; } p;
            p.s[0] = f2bf(f.x); p.s[1] = f2bf(f.y); p.s[2] = f2bf(f.z); p.s[3] = f2bf(f.w);
            *(uint2*)(xbf + ((size_t)bz * CIN + c0 + c) * NSP + n0 + nl) = p.u;
        }
    }
    __syncthreads();
    {
        const int cl4 = (t & 15) * 4, nl = t >> 4;
        #pragma unroll
        for (int i = 0; i < 4; i++) {
            int n = nl + i * 16;
            union { unsigned short s[4]; uint2 u; } p;
            #pragma unroll
            for (int j = 0; j < 4; j++)
                p.s[j] = f2bf(tile[(cl4 + j) * 65 + n]);
            *(uint2*)(xT + ((size_t)bz * NSP + n0 + n) * CIN + c0 + cl4) = p.u;
        }
    }
}

// ---------------- K1: expk = exp(Wk @ x) (C^T: M=n, N=d), BK=64 swizzled ------------
__global__ __launch_bounds__(256) void k_k(const unsigned short* __restrict__ wbf,
                                           const unsigned short* __restrict__ xT,
                                           unsigned short* __restrict__ expk,
                                           float* __restrict__ zacc,
                                           float* __restrict__ Sacc) {
    __shared__ __align__(16) unsigned short As[128 * 64];   // n-rows (xT)
    __shared__ __align__(16) unsigned short Bs[128 * 64];   // d-rows (wbf)
    const int t = threadIdx.x;
    const int id = blockIdx.x;
    // zero Sacc (8.4 MB): exactly one float4 per thread across the 2048-block grid
    ((float4*)Sacc)[(size_t)id * 256 + t] = make_float4(0.f, 0.f, 0.f, 0.f);

    const int bz = id >> 7;
    const int r7 = id & 127;
    const int xcd = r7 & 7, s7 = r7 >> 3;
    const int bn = (xcd << 2) | (s7 & 3);
    const int bm = s7 >> 2;
    const int d0 = bm * 128, n0 = bn * 128;
    const int lane = t & 63, wv = t >> 6;
    const int quad = lane >> 4, l15 = lane & 15;
    const int wmN = (wv & 1) * 64, wnD = (wv >> 1) * 64;

    const int srow8 = lane >> 3, sslot = lane & 7;
    const int scol = ((sslot - srow8) & 7) * 8;
    const int sw0 = ((quad + l15) & 7) * 8;

    const unsigned short* Ag = xT + ((size_t)bz * NSP + n0 + wv * 32 + srow8) * CIN + scol;
    const unsigned short* Bg = wbf + (size_t)(512 + d0 + wv * 32 + srow8) * CIN + scol;
    unsigned short* Al = As + wv * 32 * 64;
    unsigned short* Bl = Bs + wv * 32 * 64;

    v4f acc[4][4];
    #pragma unroll
    for (int i = 0; i < 4; i++)
        #pragma unroll
        for (int j = 0; j < 4; j++) acc[i][j] = (v4f)0.f;

    for (int kk = 0; kk < CIN; kk += 64) {
        #pragma unroll
        for (int cc = 0; cc < 4; cc++) {
            gld_lds16(Ag + (size_t)(cc * 8) * CIN + kk, Al + cc * 8 * 64);
            gld_lds16(Bg + (size_t)(cc * 8) * CIN + kk, Bl + cc * 8 * 64);
        }
        __syncthreads();
        #pragma unroll
        for (int h = 0; h < 2; h++) {
            const int sw = sw0 ^ (h * 32);
            v8s af[4], bfr[4];
            #pragma unroll
            for (int mi = 0; mi < 4; mi++) {
                union { v8s v; uint4 u; } rr;
                rr.u = *(const uint4*)(&As[(wmN + mi * 16 + l15) * 64 + sw]);
                af[mi] = rr.v;
            }
            #pragma unroll
            for (int ni = 0; ni < 4; ni++) {
                union { v8s v; uint4 u; } rr;
                rr.u = *(const uint4*)(&Bs[(wnD + ni * 16 + l15) * 64 + sw]);
                bfr[ni] = rr.v;
            }
            #pragma unroll
            for (int mi = 0; mi < 4; mi++)
                #pragma unroll
                for (int ni = 0; ni < 4; ni++)
                    acc[mi][ni] = __builtin_amdgcn_mfma_f32_16x16x32_bf16(af[mi], bfr[ni], acc[mi][ni], 0, 0, 0);
        }
        __syncthreads();
    }

    // epilogue: exp + coalesced uint2 stores + atomic z
    float za[4] = {0.f, 0.f, 0.f, 0.f};
    #pragma unroll
    for (int ni = 0; ni < 4; ni++) {
        const int d = d0 + wnD + ni * 16 + l15;
        #pragma unroll
        for (int mi = 0; mi < 4; mi++) {
            const int nb = n0 + wmN + mi * 16 + quad * 4;
            union { unsigned short s[4]; uint2 u; } p;
            #pragma unroll
            for (int rr = 0; rr < 4; rr++) {
                float e = __expf(acc[mi][ni][rr]);
                za[ni] += e;
                p.s[rr] = f2bf(e);
            }
            *(uint2*)(expk + ((size_t)bz * 512 + d) * NSP + nb) = p.u;
        }
    }
    #pragma unroll
    for (int ni = 0; ni < 4; ni++) {
        float z = za[ni];
        z += __shfl_xor(z, 16);
        z += __shfl_xor(z, 32);
        if (quad == 0)
            atomicAdd(&zacc[bz * 512 + d0 + wnD + ni * 16 + l15], z);
    }
}

// ---------------- K2: S[d][c] += expk[d][n]*x[c][n], split-K atomics, BK=64 ---------
__global__ __launch_bounds__(256) void k_S(const unsigned short* __restrict__ expk,
                                           const unsigned short* __restrict__ xbf,
                                           float* __restrict__ Sacc) {
    __shared__ __align__(16) unsigned short As[128 * 64];   // c-rows (xbf)
    __shared__ __align__(16) unsigned short Bs[128 * 64];   // d-rows (expk)
    const int t = threadIdx.x;
    const int id = blockIdx.x;              // 0..511
    const int hc = id >> 6;
    const int h = hc >> 1, ch = hc & 1;
    const int bkc = id & 63;
    const int b = bkc >> 2, kc = bkc & 3;
    const int kw = kc * 1024;
    const int lane = t & 63, wv = t >> 6, quad = lane >> 4, l15 = lane & 15;
    const int wmC = (wv & 1) * 64, wnD = (wv >> 1) * 64;

    const int srow8 = lane >> 3, sslot = lane & 7;
    const int scol = ((sslot - srow8) & 7) * 8;
    const int sw0 = ((quad + l15) & 7) * 8;

    const unsigned short* Ag = xbf + ((size_t)b * CIN + ch * 128 + wv * 32 + srow8) * NSP + kw + scol;
    const unsigned short* Bg = expk + ((size_t)b * 512 + h * 128 + wv * 32 + srow8) * NSP + kw + scol;
    unsigned short* Al = As + wv * 32 * 64;
    unsigned short* Bl = Bs + wv * 32 * 64;

    v4f acc[4][4];
    #pragma unroll
    for (int i = 0; i < 4; i++)
        #pragma unroll
        for (int j = 0; j < 4; j++) acc[i][j] = (v4f)0.f;

    for (int kk = 0; kk < 1024; kk += 64) {
        #pragma unroll
        for (int cc = 0; cc < 4; cc++) {
            gld_lds16(Ag + (size_t)(cc * 8) * NSP + kk, Al + cc * 8 * 64);
            gld_lds16(Bg + (size_t)(cc * 8) * NSP + kk, Bl + cc * 8 * 64);
        }
        __syncthreads();
        #pragma unroll
        for (int h2 = 0; h2 < 2; h2++) {
            const int sw = sw0 ^ (h2 * 32);
            v8s af[4], bfr[4];
            #pragma unroll
            for (int mi = 0; mi < 4; mi++) {
                union { v8s v; uint4 u; } rr;
                rr.u = *(const uint4*)(&As[(wmC + mi * 16 + l15) * 64 + sw]);
                af[mi] = rr.v;
            }
            #pragma unroll
            for (int ni = 0; ni < 4; ni++) {
                union { v8s v; uint4 u; } rr;
                rr.u = *(const uint4*)(&Bs[(wnD + ni * 16 + l15) * 64 + sw]);
                bfr[ni] = rr.v;
            }
            #pragma unroll
            for (int mi = 0; mi < 4; mi++)
                #pragma unroll
                for (int ni = 0; ni < 4; ni++)
                    acc[mi][ni] = __builtin_amdgcn_mfma_f32_16x16x32_bf16(af[mi], bfr[ni], acc[mi][ni], 0, 0, 0);
        }
        __syncthreads();
    }

    // atomic accumulate into Sacc[bh][d][256c]
    const int bh = b * 4 + h;
    float* outp = Sacc + (size_t)bh * 32768;
    #pragma unroll
    for (int ni = 0; ni < 4; ni++) {
        const int d = wnD + ni * 16 + l15;
        #pragma unroll
        for (int mi = 0; mi < 4; mi++) {
            const int c = ch * 128 + wmC + mi * 16 + quad * 4;
            #pragma unroll
            for (int rr = 0; rr < 4; rr++)
                atomicAdd(&outp[d * 256 + c + rr], acc[mi][ni][rr]);
        }
    }
}

// ---------------- K4: per bh: ctx = (Sacc @ Wv^T)*zinv; Wc = w_out @ ctx^T ----------
__global__ __launch_bounds__(256) void k_redwc(const float* __restrict__ Sacc,
                                               const float* __restrict__ zacc,
                                               const unsigned short* __restrict__ wbf,
                                               const float* __restrict__ w_out,
                                               unsigned short* __restrict__ Wc) {
    __shared__ unsigned short Ds[128 * 136];   // ctx bf16 [d][e]
    __shared__ float zinv[128];
    const int t = threadIdx.x;
    const int bh = blockIdx.x;  const int b = bh >> 2, h = bh & 3;
    const int lane = t & 63, wv = t >> 6, quad = lane >> 4, l15 = lane & 15;

    if (t < 128) zinv[t] = 1.0f / zacc[b * 512 + h * 128 + t];
    __syncthreads();

    // GEMM-A: ctx[d][e] = sum_c S[d][c] * Wv_h[e][c]   (S staged from fp32)
    {
        const int wm = (wv & 1) * 64, wn = (wv >> 1) * 64;
        const float* Sb = Sacc + (size_t)bh * 32768;
        const unsigned short* Vb = wbf + (size_t)(1024 + h * 128) * CIN;
        v4f acc[4][4];
        #pragma unroll
        for (int i = 0; i < 4; i++)
            #pragma unroll
            for (int j = 0; j < 4; j++) acc[i][j] = (v4f)0.f;
        for (int kk = 0; kk < CIN; kk += 32) {
            v8s af[4], bfr[4];
            #pragma unroll
            for (int mi = 0; mi < 4; mi++) {
                const float* sp = Sb + (size_t)(wm + mi * 16 + l15) * 256 + kk + quad * 8;
                float4 f0 = *(const float4*)sp;
                float4 f1 = *(const float4*)(sp + 4);
                union { v8s v; unsigned short s[8]; } r;
                r.s[0] = f2bf(f0.x); r.s[1] = f2bf(f0.y); r.s[2] = f2bf(f0.z); r.s[3] = f2bf(f0.w);
                r.s[4] = f2bf(f1.x); r.s[5] = f2bf(f1.y); r.s[6] = f2bf(f1.z); r.s[7] = f2bf(f1.w);
                af[mi] = r.v;
            }
            #pragma unroll
            for (int ni = 0; ni < 4; ni++) {
                union { v8s v; uint4 u; } rr;
                rr.u = *(const uint4*)(Vb + (size_t)(wn + ni * 16 + l15) * 256 + kk + quad * 8);
                bfr[ni] = rr.v;
            }
            #pragma unroll
            for (int mi = 0; mi < 4; mi++)
                #pragma unroll
                for (int ni = 0; ni < 4; ni++)
                    acc[mi][ni] = __builtin_amdgcn_mfma_f32_16x16x32_bf16(af[mi], bfr[ni], acc[mi][ni], 0, 0, 0);
        }
        float zq[4][4];
        #pragma unroll
        for (int mi = 0; mi < 4; mi++)
            #pragma unroll
            for (int rr = 0; rr < 4; rr++)
                zq[mi][rr] = zinv[wm + mi * 16 + quad * 4 + rr];
        #pragma unroll
        for (int mi = 0; mi < 4; mi++)
            #pragma unroll
            for (int ni = 0; ni < 4; ni++)
                #pragma unroll
                for (int rr = 0; rr < 4; rr++)
                    Ds[(wm + mi * 16 + quad * 4 + rr) * 136 + wn + ni * 16 + l15] =
                        f2bf(acc[mi][ni][rr] * zq[mi][rr]);
    }
    __syncthreads();

    // GEMM-B: Wc_h[o][d] = sum_e w_out[o][h*128+e] * ctx[d][e]
    {
        const int wm = wv * 64;
        v4f acc[4][8];
        #pragma unroll
        for (int i = 0; i < 4; i++)
            #pragma unroll
            for (int j = 0; j < 8; j++) acc[i][j] = (v4f)0.f;
        for (int kk = 0; kk < 128; kk += 32) {
            v8s af[4], bfr[8];
            #pragma unroll
            for (int mi = 0; mi < 4; mi++) {
                int o = wm + mi * 16 + l15;
                const float* wp = w_out + (size_t)o * HID + h * 128 + kk + quad * 8;
                float4 f0 = *(const float4*)wp;
                float4 f1 = *(const float4*)(wp + 4);
                union { v8s v; unsigned short s[8]; } r;
                r.s[0] = f2bf(f0.x); r.s[1] = f2bf(f0.y); r.s[2] = f2bf(f0.z); r.s[3] = f2bf(f0.w);
                r.s[4] = f2bf(f1.x); r.s[5] = f2bf(f1.y); r.s[6] = f2bf(f1.z); r.s[7] = f2bf(f1.w);
                af[mi] = r.v;
            }
            #pragma unroll
            for (int ni = 0; ni < 8; ni++) {
                union { v8s v; uint4 u; } r;
                r.u = *(const uint4*)(&Ds[(ni * 16 + l15) * 136 + kk + quad * 8]);
                bfr[ni] = r.v;
            }
            #pragma unroll
            for (int mi = 0; mi < 4; mi++)
                #pragma unroll
                for (int ni = 0; ni < 8; ni++)
                    acc[mi][ni] = __builtin_amdgcn_mfma_f32_16x16x32_bf16(af[mi], bfr[ni], acc[mi][ni], 0, 0, 0);
        }
        #pragma unroll
        for (int ni = 0; ni < 8; ni++) {
            int d = ni * 16 + l15;
            #pragma unroll
            for (int mi = 0; mi < 4; mi++)
                #pragma unroll
                for (int rr = 0; rr < 4; rr++) {
                    int o = wm + mi * 16 + quad * 4 + rr;
                    Wc[((size_t)b * 256 + o) * HID + h * 128 + d] = f2bf(acc[mi][ni][rr]);
                }
        }
    }
}

// ---------------- K5: Weff = Wc @ wq_q^T (C^T: M=c, N=o), BK=64 swizzled ------------
__global__ __launch_bounds__(256) void k_chain(const unsigned short* __restrict__ Wc,
                                               const unsigned short* __restrict__ wqT,
                                               unsigned short* __restrict__ Weff) {
    __shared__ __align__(16) unsigned short As[128 * 64];   // c-rows (wqT)
    __shared__ __align__(16) unsigned short Bs[128 * 64];   // o-rows (Wc)
    const int t = threadIdx.x;
    const int c0 = blockIdx.x * 128, o0 = blockIdx.y * 128, bz = blockIdx.z;
    const int lane = t & 63, wv = t >> 6, quad = lane >> 4, l15 = lane & 15;
    const int wmC = (wv & 1) * 64, wnO = (wv >> 1) * 64;

    const int srow8 = lane >> 3, sslot = lane & 7;
    const int scol = ((sslot - srow8) & 7) * 8;
    const int sw0 = ((quad + l15) & 7) * 8;

    const unsigned short* Ag = wqT + (size_t)(c0 + wv * 32 + srow8) * HID + scol;
    const unsigned short* Bg = Wc + ((size_t)bz * 256 + o0 + wv * 32 + srow8) * HID + scol;
    unsigned short* Al = As + wv * 32 * 64;
    unsigned short* Bl = Bs + wv * 32 * 64;

    v4f acc[4][4];
    #pragma unroll
    for (int i = 0; i < 4; i++)
        #pragma unroll
        for (int j = 0; j < 4; j++) acc[i][j] = (v4f)0.f;

    for (int kk = 0; kk < HID; kk += 64) {
        #pragma unroll
        for (int cc = 0; cc < 4; cc++) {
            gld_lds16(Ag + (size_t)(cc * 8) * HID + kk, Al + cc * 8 * 64);
            gld_lds16(Bg + (size_t)(cc * 8) * HID + kk, Bl + cc * 8 * 64);
        }
        __syncthreads();
        #pragma unroll
        for (int h = 0; h < 2; h++) {
            const int sw = sw0 ^ (h * 32);
            v8s af[4], bfr[4];
            #pragma unroll
            for (int mi = 0; mi < 4; mi++) {
                union { v8s v; uint4 u; } rr;
                rr.u = *(const uint4*)(&As[(wmC + mi * 16 + l15) * 64 + sw]);
                af[mi] = rr.v;
            }
            #pragma unroll
            for (int ni = 0; ni < 4; ni++) {
                union { v8s v; uint4 u; } rr;
                rr.u = *(const uint4*)(&Bs[(wnO + ni * 16 + l15) * 64 + sw]);
                bfr[ni] = rr.v;
            }
            #pragma unroll
            for (int mi = 0; mi < 4; mi++)
                #pragma unroll
                for (int ni = 0; ni < 4; ni++)
                    acc[mi][ni] = __builtin_amdgcn_mfma_f32_16x16x32_bf16(af[mi], bfr[ni], acc[mi][ni], 0, 0, 0);
        }
        __syncthreads();
    }
    #pragma unroll
    for (int ni = 0; ni < 4; ni++) {
        const int o = o0 + wnO + ni * 16 + l15;
        #pragma unroll
        for (int mi = 0; mi < 4; mi++) {
            const int c = c0 + wmC + mi * 16 + quad * 4;
            union { unsigned short s[4]; uint2 u; } p;
            #pragma unroll
            for (int rr = 0; rr < 4; rr++) p.s[rr] = f2bf(acc[mi][ni][rr]);
            *(uint2*)(Weff + ((size_t)bz * 256 + o) * 256 + c) = p.u;
        }
    }
}

// ---------------- K6: y = Weff @ x + b_out (C^T: M=n, N=o), BK=64 swizzled ----------
__global__ __launch_bounds__(256) void k_y(const unsigned short* __restrict__ Weff,
                                           const unsigned short* __restrict__ xT,
                                           const float* __restrict__ b_out,
                                           float* __restrict__ y) {
    __shared__ __align__(16) unsigned short As[128 * 64];   // n-rows (xT)
    __shared__ __align__(16) unsigned short Bs[128 * 64];   // o-rows (Weff)
    const int t = threadIdx.x;
    const int o0 = blockIdx.x * 128;
    const int n0 = blockIdx.y * 128;
    const int bz = blockIdx.z;
    const int lane = t & 63, wv = t >> 6, quad = lane >> 4, l15 = lane & 15;
    const int wmN = (wv & 1) * 64, wnO = (wv >> 1) * 64;

    const int srow8 = lane >> 3, sslot = lane & 7;
    const int scol = ((sslot - srow8) & 7) * 8;
    const int sw0 = ((quad + l15) & 7) * 8;

    const unsigned short* Ag = xT + ((size_t)bz * NSP + n0 + wv * 32 + srow8) * CIN + scol;
    const unsigned short* Bg = Weff + ((size_t)bz * 256 + o0 + wv * 32 + srow8) * CIN + scol;
    unsigned short* Al = As + wv * 32 * 64;
    unsigned short* Bl = Bs + wv * 32 * 64;

    v4f acc[4][4];
    #pragma unroll
    for (int i = 0; i < 4; i++)
        #pragma unroll
        for (int j = 0; j < 4; j++) acc[i][j] = (v4f)0.f;

    for (int kk = 0; kk < CIN; kk += 64) {
        #pragma unroll
        for (int cc = 0; cc < 4; cc++) {
            gld_lds16(Ag + (size_t)(cc * 8) * CIN + kk, Al + cc * 8 * 64);
            gld_lds16(Bg + (size_t)(cc * 8) * CIN + kk, Bl + cc * 8 * 64);
        }
        __syncthreads();
        #pragma unroll
        for (int h = 0; h < 2; h++) {
            const int sw = sw0 ^ (h * 32);
            v8s af[4], bfr[4];
            #pragma unroll
            for (int mi = 0; mi < 4; mi++) {
                union { v8s v; uint4 u; } rr;
                rr.u = *(const uint4*)(&As[(wmN + mi * 16 + l15) * 64 + sw]);
                af[mi] = rr.v;
            }
            #pragma unroll
            for (int ni = 0; ni < 4; ni++) {
                union { v8s v; uint4 u; } rr;
                rr.u = *(const uint4*)(&Bs[(wnO + ni * 16 + l15) * 64 + sw]);
                bfr[ni] = rr.v;
            }
            #pragma unroll
            for (int mi = 0; mi < 4; mi++)
                #pragma unroll
                for (int ni = 0; ni < 4; ni++)
                    acc[mi][ni] = __builtin_amdgcn_mfma_f32_16x16x32_bf16(af[mi], bfr[ni], acc[mi][ni], 0, 0, 0);
        }
        __syncthreads();
    }
    #pragma unroll
    for (int ni = 0; ni < 4; ni++) {
        const int o = o0 + wnO + ni * 16 + l15;
        const float bias = b_out[o];
        #pragma unroll
        for (int mi = 0; mi < 4; mi++) {
            const int n = n0 + wmN + mi * 16 + quad * 4;
            v4f v = acc[mi][ni];
            v[0] += bias; v[1] += bias; v[2] += bias; v[3] += bias;
            *(v4f*)(y + ((size_t)bz * 256 + o) * NSP + n) = v;
        }
    }
}

extern "C" void kernel_launch(void* const* d_in, const int* in_sizes, int n_in,
                              void* d_out, int out_size, void* d_ws, size_t ws_size,
                              hipStream_t stream) {
    (void)in_sizes; (void)n_in; (void)out_size; (void)ws_size;
    const float* x     = (const float*)d_in[0];
    const float* w_qkv = (const float*)d_in[1];
    const float* w_out = (const float*)d_in[2];
    const float* b_out = (const float*)d_in[3];
    float* y = (float*)d_out;
    char* ws = (char*)d_ws;

    unsigned short* xT   = (unsigned short*)(ws);                 //  33,554,432 B
    unsigned short* xbf  = (unsigned short*)(ws + 33554432);      //  33,554,432 B
    unsigned short* expk = (unsigned short*)(ws + 67108864);      //  67,108,864 B
    float*          Sacc = (float*)(ws + 134217728);              //   8,388,608 B
    float*          zacc = (float*)(ws + 142606336);              //      32,768 B
    unsigned short* Wc   = (unsigned short*)(ws + 142639104);     //   4,194,304 B
    unsigned short* Weff = (unsigned short*)(ws + 146833408);     //   2,097,152 B
    unsigned short* wbf  = (unsigned short*)(ws + 148930560);     //     786,432 B
    unsigned short* wqT  = (unsigned short*)(ws + 149716992);     //     524,288 B

    k_prep <<<dim3(4352),       256, 0, stream>>>(x, w_qkv, xbf, xT, wbf, wqT, zacc);
    k_k    <<<dim3(2048),       256, 0, stream>>>(wbf, xT, expk, zacc, Sacc);
    k_S    <<<dim3(512),        256, 0, stream>>>(expk, xbf, Sacc);
    k_redwc<<<dim3(64),         256, 0, stream>>>(Sacc, zacc, wbf, w_out, Wc);
    k_chain<<<dim3(2, 2, 16),   256, 0, stream>>>(Wc, wqT, Weff);
    k_y    <<<dim3(2, 32, 16),  256, 0, stream>>>(Weff, xT, b_out, y);
}

// Round 8
// 250.959 us; speedup vs baseline: 1.3420x; 1.3420x over previous
//
#include <hip/hip_runtime.h>

#define BATCH 16
#define CIN   256
#define NSP   4096
#define HID   512

typedef short v8s __attribute__((ext_vector_type(8)));
typedef float v4f __attribute__((ext_vector_type(4)));

__device__ __forceinline__ unsigned short f2bf(float f) {
    union { float f; unsigned u; } a; a.f = f;
    unsigned r = a.u + 0x7fffu + ((a.u >> 16) & 1u);
    return (unsigned short)(r >> 16);
}

__device__ __forceinline__ void gld_lds16(const unsigned short* g, unsigned short* l) {
    __builtin_amdgcn_global_load_lds(
        (const __attribute__((address_space(1))) unsigned int*)g,
        (__attribute__((address_space(3))) unsigned int*)l,
        16, 0, 0);
}

// Swizzled 128x64 bf16 LDS tile: slot s (8 shorts) of row r stored at slot (s+r)&7.
// Staging lane (srow8=lane>>3, sslot=lane&7) loads global col ((sslot-srow8)&7)*8.
// Reader of (row r, k-half h): LDS col = ((quad + r)&7)*8 ^ (h*32).  0 conflicts (R7 PMC).

// ---------------- P: weights prep + x prep + zacc zero (merged) ---------------------
__global__ __launch_bounds__(256) void k_prep(const float* __restrict__ x,
                                              const float* __restrict__ wq,
                                              unsigned short* __restrict__ xbf,
                                              unsigned short* __restrict__ xT,
                                              unsigned short* __restrict__ wbf,
                                              unsigned short* __restrict__ wqT,
                                              float* __restrict__ zacc) {
    const int bid = blockIdx.x;
    const int t = threadIdx.x;
    if (bid >= 4320) {                        // 32 blocks: zero zacc (16x512 fp32)
        zacc[(bid - 4320) * 256 + t] = 0.f;
        return;
    }
    if (bid >= 4096) {
        const int wid = bid - 4096;
        if (wid < 192) {                      // bf16 convert of full w_qkv
            const int g = wid * 256 + t;
            const float4 f0 = *(const float4*)(wq + (size_t)g * 8);
            const float4 f1 = *(const float4*)(wq + (size_t)g * 8 + 4);
            union { unsigned short s[8]; uint4 u; } p;
            p.s[0] = f2bf(f0.x); p.s[1] = f2bf(f0.y); p.s[2] = f2bf(f0.z); p.s[3] = f2bf(f0.w);
            p.s[4] = f2bf(f1.x); p.s[5] = f2bf(f1.y); p.s[6] = f2bf(f1.z); p.s[7] = f2bf(f1.w);
            *(uint4*)(wbf + (size_t)g * 8) = p.u;
            return;
        }
        __shared__ float tile[64 * 65];       // 32 blocks: wqT transpose (q part)
        const int bb = wid - 192;
        const int u0 = (bb & 7) * 64, c0 = (bb >> 3) * 64;
        {
            const int cl = (t & 15) * 4, ul = t >> 4;
            #pragma unroll
            for (int i = 0; i < 4; i++) {
                int u = ul + i * 16;
                const float4 f = *(const float4*)(wq + (size_t)(u0 + u) * CIN + c0 + cl);
                *(float4*)(&tile[u * 65 + cl]) = f;
            }
        }
        __syncthreads();
        {
            const int ul4 = (t & 15) * 4, cl = t >> 4;
            #pragma unroll
            for (int i = 0; i < 4; i++) {
                int c = cl + i * 16;
                union { unsigned short s[4]; uint2 u; } p;
                #pragma unroll
                for (int j = 0; j < 4; j++)
                    p.s[j] = f2bf(tile[(ul4 + j) * 65 + c]);
                *(uint2*)(wqT + (size_t)(c0 + c) * HID + u0 + ul4) = p.u;
            }
        }
        return;
    }
    // x prep: 4096 blocks of 64x64 tiles
    __shared__ float tile[64 * 65];
    const int n0 = (bid & 63) * 64, c0 = ((bid >> 6) & 3) * 64, bz = bid >> 8;
    const float* xb = x + (size_t)bz * CIN * NSP;
    {
        const int nl = (t & 15) * 4, cl = t >> 4;
        #pragma unroll
        for (int i = 0; i < 4; i++) {
            int c = cl + i * 16;
            const float4 f = *(const float4*)(xb + (size_t)(c0 + c) * NSP + n0 + nl);
            *(float4*)(&tile[c * 65 + nl]) = f;
            union { unsigned short s[4]; uint2 u; } p;
            p.s[0] = f2bf(f.x); p.s[1] = f2bf(f.y); p.s[2] = f2bf(f.z); p.s[3] = f2bf(f.w);
            *(uint2*)(xbf + ((size_t)bz * CIN + c0 + c) * NSP + n0 + nl) = p.u;
        }
    }
    __syncthreads();
    {
        const int cl4 = (t & 15) * 4, nl = t >> 4;
        #pragma unroll
        for (int i = 0; i < 4; i++) {
            int n = nl + i * 16;
            union { unsigned short s[4]; uint2 u; } p;
            #pragma unroll
            for (int j = 0; j < 4; j++)
                p.s[j] = f2bf(tile[(cl4 + j) * 65 + n]);
            *(uint2*)(xT + ((size_t)bz * NSP + n0 + n) * CIN + c0 + cl4) = p.u;
        }
    }
}

// ---------------- K1: expk = exp(Wk @ x) (C^T: M=n, N=d), BK=64 swizzled ------------
__global__ __launch_bounds__(256) void k_k(const unsigned short* __restrict__ wbf,
                                           const unsigned short* __restrict__ xT,
                                           unsigned short* __restrict__ expk,
                                           float* __restrict__ zacc) {
    __shared__ __align__(16) unsigned short As[128 * 64];   // n-rows (xT)
    __shared__ __align__(16) unsigned short Bs[128 * 64];   // d-rows (wbf)
    const int t = threadIdx.x;
    const int id = blockIdx.x;
    const int bz = id >> 7;
    const int r7 = id & 127;
    const int xcd = r7 & 7, s7 = r7 >> 3;
    const int bn = (xcd << 2) | (s7 & 3);
    const int bm = s7 >> 2;
    const int d0 = bm * 128, n0 = bn * 128;
    const int lane = t & 63, wv = t >> 6;
    const int quad = lane >> 4, l15 = lane & 15;
    const int wmN = (wv & 1) * 64, wnD = (wv >> 1) * 64;

    const int srow8 = lane >> 3, sslot = lane & 7;
    const int scol = ((sslot - srow8) & 7) * 8;
    const int sw0 = ((quad + l15) & 7) * 8;

    const unsigned short* Ag = xT + ((size_t)bz * NSP + n0 + wv * 32 + srow8) * CIN + scol;
    const unsigned short* Bg = wbf + (size_t)(512 + d0 + wv * 32 + srow8) * CIN + scol;
    unsigned short* Al = As + wv * 32 * 64;
    unsigned short* Bl = Bs + wv * 32 * 64;

    v4f acc[4][4];
    #pragma unroll
    for (int i = 0; i < 4; i++)
        #pragma unroll
        for (int j = 0; j < 4; j++) acc[i][j] = (v4f)0.f;

    for (int kk = 0; kk < CIN; kk += 64) {
        #pragma unroll
        for (int cc = 0; cc < 4; cc++) {
            gld_lds16(Ag + (size_t)(cc * 8) * CIN + kk, Al + cc * 8 * 64);
            gld_lds16(Bg + (size_t)(cc * 8) * CIN + kk, Bl + cc * 8 * 64);
        }
        __syncthreads();
        #pragma unroll
        for (int h = 0; h < 2; h++) {
            const int sw = sw0 ^ (h * 32);
            v8s af[4], bfr[4];
            #pragma unroll
            for (int mi = 0; mi < 4; mi++) {
                union { v8s v; uint4 u; } rr;
                rr.u = *(const uint4*)(&As[(wmN + mi * 16 + l15) * 64 + sw]);
                af[mi] = rr.v;
            }
            #pragma unroll
            for (int ni = 0; ni < 4; ni++) {
                union { v8s v; uint4 u; } rr;
                rr.u = *(const uint4*)(&Bs[(wnD + ni * 16 + l15) * 64 + sw]);
                bfr[ni] = rr.v;
            }
            #pragma unroll
            for (int mi = 0; mi < 4; mi++)
                #pragma unroll
                for (int ni = 0; ni < 4; ni++)
                    acc[mi][ni] = __builtin_amdgcn_mfma_f32_16x16x32_bf16(af[mi], bfr[ni], acc[mi][ni], 0, 0, 0);
        }
        __syncthreads();
    }

    // epilogue: exp + coalesced uint2 stores + atomic z (low contention, R7-verified)
    float za[4] = {0.f, 0.f, 0.f, 0.f};
    #pragma unroll
    for (int ni = 0; ni < 4; ni++) {
        const int d = d0 + wnD + ni * 16 + l15;
        #pragma unroll
        for (int mi = 0; mi < 4; mi++) {
            const int nb = n0 + wmN + mi * 16 + quad * 4;
            union { unsigned short s[4]; uint2 u; } p;
            #pragma unroll
            for (int rr = 0; rr < 4; rr++) {
                float e = __expf(acc[mi][ni][rr]);
                za[ni] += e;
                p.s[rr] = f2bf(e);
            }
            *(uint2*)(expk + ((size_t)bz * 512 + d) * NSP + nb) = p.u;
        }
    }
    #pragma unroll
    for (int ni = 0; ni < 4; ni++) {
        float z = za[ni];
        z += __shfl_xor(z, 16);
        z += __shfl_xor(z, 32);
        if (quad == 0)
            atomicAdd(&zacc[bz * 512 + d0 + wnD + ni * 16 + l15], z);
    }
}

// ---------------- K2: S partials (C^T: M=c, N=d), BK=64 swizzled, float4 stores -----
__global__ __launch_bounds__(256) void k_S(const unsigned short* __restrict__ expk,
                                           const unsigned short* __restrict__ xbf,
                                           float* __restrict__ Sp) {
    __shared__ __align__(16) unsigned short As[128 * 64];   // c-rows (xbf)
    __shared__ __align__(16) unsigned short Bs[128 * 64];   // d-rows (expk)
    const int t = threadIdx.x;
    const int id = blockIdx.x;              // 0..511
    const int hc = id >> 6;
    const int h = hc >> 1, ch = hc & 1;
    const int bkc = id & 63;
    const int b = bkc >> 2, kc = bkc & 3;
    const int kw = kc * 1024;
    const int lane = t & 63, wv = t >> 6, quad = lane >> 4, l15 = lane & 15;
    const int wmC = (wv & 1) * 64, wnD = (wv >> 1) * 64;

    const int srow8 = lane >> 3, sslot = lane & 7;
    const int scol = ((sslot - srow8) & 7) * 8;
    const int sw0 = ((quad + l15) & 7) * 8;

    const unsigned short* Ag = xbf + ((size_t)b * CIN + ch * 128 + wv * 32 + srow8) * NSP + kw + scol;
    const unsigned short* Bg = expk + ((size_t)b * 512 + h * 128 + wv * 32 + srow8) * NSP + kw + scol;
    unsigned short* Al = As + wv * 32 * 64;
    unsigned short* Bl = Bs + wv * 32 * 64;

    v4f acc[4][4];
    #pragma unroll
    for (int i = 0; i < 4; i++)
        #pragma unroll
        for (int j = 0; j < 4; j++) acc[i][j] = (v4f)0.f;

    for (int kk = 0; kk < 1024; kk += 64) {
        #pragma unroll
        for (int cc = 0; cc < 4; cc++) {
            gld_lds16(Ag + (size_t)(cc * 8) * NSP + kk, Al + cc * 8 * 64);
            gld_lds16(Bg + (size_t)(cc * 8) * NSP + kk, Bl + cc * 8 * 64);
        }
        __syncthreads();
        #pragma unroll
        for (int h2 = 0; h2 < 2; h2++) {
            const int sw = sw0 ^ (h2 * 32);
            v8s af[4], bfr[4];
            #pragma unroll
            for (int mi = 0; mi < 4; mi++) {
                union { v8s v; uint4 u; } rr;
                rr.u = *(const uint4*)(&As[(wmC + mi * 16 + l15) * 64 + sw]);
                af[mi] = rr.v;
            }
            #pragma unroll
            for (int ni = 0; ni < 4; ni++) {
                union { v8s v; uint4 u; } rr;
                rr.u = *(const uint4*)(&Bs[(wnD + ni * 16 + l15) * 64 + sw]);
                bfr[ni] = rr.v;
            }
            #pragma unroll
            for (int mi = 0; mi < 4; mi++)
                #pragma unroll
                for (int ni = 0; ni < 4; ni++)
                    acc[mi][ni] = __builtin_amdgcn_mfma_f32_16x16x32_bf16(af[mi], bfr[ni], acc[mi][ni], 0, 0, 0);
        }
        __syncthreads();
    }

    // Sp layout: [(bh*2+ch)*4 + kc][128 d][128 c] fp32; lane's 4 vals = consecutive c
    const int bh = b * 4 + h;
    float* outp = Sp + ((size_t)(bh * 2 + ch) * 4 + kc) * 16384;
    #pragma unroll
    for (int ni = 0; ni < 4; ni++) {
        const int d = wnD + ni * 16 + l15;
        #pragma unroll
        for (int mi = 0; mi < 4; mi++) {
            const int c = wmC + mi * 16 + quad * 4;
            *(v4f*)(outp + d * 128 + c) = acc[mi][ni];
        }
    }
}

// ---------------- K3: reduce S partials -> Sred bf16 [bh][128 d][256 c] -------------
__global__ __launch_bounds__(256) void k_sred(const float* __restrict__ Sp,
                                              unsigned short* __restrict__ Sred) {
    const int qv = blockIdx.x * 256 + threadIdx.x;   // 524288 quads
    const int bh = qv >> 13, r = qv & 8191;
    const int dl = r >> 6, cq6 = r & 63;
    const int ch = cq6 >> 5, clq = cq6 & 31;
    const float* p = Sp + ((size_t)(bh * 2 + ch) * 4) * 16384 + dl * 128 + clq * 4;
    float4 s = *(const float4*)p;
    #pragma unroll
    for (int kc = 1; kc < 4; kc++) {
        const float4 f = *(const float4*)(p + (size_t)kc * 16384);
        s.x += f.x; s.y += f.y; s.z += f.z; s.w += f.w;
    }
    union { unsigned short us[4]; uint2 u; } pk;
    pk.us[0] = f2bf(s.x); pk.us[1] = f2bf(s.y); pk.us[2] = f2bf(s.z); pk.us[3] = f2bf(s.w);
    *(uint2*)(Sred + (size_t)bh * 32768 + dl * 256 + cq6 * 4) = pk.u;
}

// ---------------- K4: per bh: ctx = (Sred @ Wv^T)*zinv; Wc = w_out @ ctx^T ----------
__global__ __launch_bounds__(256) void k_redwc(const unsigned short* __restrict__ Sred,
                                               const float* __restrict__ zacc,
                                               const unsigned short* __restrict__ wbf,
                                               const float* __restrict__ w_out,
                                               unsigned short* __restrict__ Wc) {
    __shared__ unsigned short Ds[128 * 136];   // ctx bf16 [d][e]
    __shared__ float zinv[128];
    const int t = threadIdx.x;
    const int bh = blockIdx.x;  const int b = bh >> 2, h = bh & 3;
    const int lane = t & 63, wv = t >> 6, quad = lane >> 4, l15 = lane & 15;

    if (t < 128) zinv[t] = 1.0f / zacc[b * 512 + h * 128 + t];
    __syncthreads();

    // GEMM-A: ctx[d][e] = sum_c Sred[d][c] * Wv_h[e][c]
    {
        const int wm = (wv & 1) * 64, wn = (wv >> 1) * 64;
        const unsigned short* Sb = Sred + (size_t)bh * 32768;
        const unsigned short* Vb = wbf + (size_t)(1024 + h * 128) * CIN;
        v4f acc[4][4];
        #pragma unroll
        for (int i = 0; i < 4; i++)
            #pragma unroll
            for (int j = 0; j < 4; j++) acc[i][j] = (v4f)0.f;
        for (int kk = 0; kk < CIN; kk += 32) {
            v8s af[4], bfr[4];
            #pragma unroll
            for (int mi = 0; mi < 4; mi++) {
                union { v8s v; uint4 u; } rr;
                rr.u = *(const uint4*)(Sb + (size_t)(wm + mi * 16 + l15) * 256 + kk + quad * 8);
                af[mi] = rr.v;
            }
            #pragma unroll
            for (int ni = 0; ni < 4; ni++) {
                union { v8s v; uint4 u; } rr;
                rr.u = *(const uint4*)(Vb + (size_t)(wn + ni * 16 + l15) * 256 + kk + quad * 8);
                bfr[ni] = rr.v;
            }
            #pragma unroll
            for (int mi = 0; mi < 4; mi++)
                #pragma unroll
                for (int ni = 0; ni < 4; ni++)
                    acc[mi][ni] = __builtin_amdgcn_mfma_f32_16x16x32_bf16(af[mi], bfr[ni], acc[mi][ni], 0, 0, 0);
        }
        float zq[4][4];
        #pragma unroll
        for (int mi = 0; mi < 4; mi++)
            #pragma unroll
            for (int rr = 0; rr < 4; rr++)
                zq[mi][rr] = zinv[wm + mi * 16 + quad * 4 + rr];
        #pragma unroll
        for (int mi = 0; mi < 4; mi++)
            #pragma unroll
            for (int ni = 0; ni < 4; ni++)
                #pragma unroll
                for (int rr = 0; rr < 4; rr++)
                    Ds[(wm + mi * 16 + quad * 4 + rr) * 136 + wn + ni * 16 + l15] =
                        f2bf(acc[mi][ni][rr] * zq[mi][rr]);
    }
    __syncthreads();

    // GEMM-B: Wc_h[o][d] = sum_e w_out[o][h*128+e] * ctx[d][e]
    {
        const int wm = wv * 64;
        v4f acc[4][8];
        #pragma unroll
        for (int i = 0; i < 4; i++)
            #pragma unroll
            for (int j = 0; j < 8; j++) acc[i][j] = (v4f)0.f;
        for (int kk = 0; kk < 128; kk += 32) {
            v8s af[4], bfr[8];
            #pragma unroll
            for (int mi = 0; mi < 4; mi++) {
                int o = wm + mi * 16 + l15;
                const float* wp = w_out + (size_t)o * HID + h * 128 + kk + quad * 8;
                float4 f0 = *(const float4*)wp;
                float4 f1 = *(const float4*)(wp + 4);
                union { v8s v; unsigned short s[8]; } r;
                r.s[0] = f2bf(f0.x); r.s[1] = f2bf(f0.y); r.s[2] = f2bf(f0.z); r.s[3] = f2bf(f0.w);
                r.s[4] = f2bf(f1.x); r.s[5] = f2bf(f1.y); r.s[6] = f2bf(f1.z); r.s[7] = f2bf(f1.w);
                af[mi] = r.v;
            }
            #pragma unroll
            for (int ni = 0; ni < 8; ni++) {
                union { v8s v; uint4 u; } r;
                r.u = *(const uint4*)(&Ds[(ni * 16 + l15) * 136 + kk + quad * 8]);
                bfr[ni] = r.v;
            }
            #pragma unroll
            for (int mi = 0; mi < 4; mi++)
                #pragma unroll
                for (int ni = 0; ni < 8; ni++)
                    acc[mi][ni] = __builtin_amdgcn_mfma_f32_16x16x32_bf16(af[mi], bfr[ni], acc[mi][ni], 0, 0, 0);
        }
        #pragma unroll
        for (int ni = 0; ni < 8; ni++) {
            int d = ni * 16 + l15;
            #pragma unroll
            for (int mi = 0; mi < 4; mi++)
                #pragma unroll
                for (int rr = 0; rr < 4; rr++) {
                    int o = wm + mi * 16 + quad * 4 + rr;
                    Wc[((size_t)b * 256 + o) * HID + h * 128 + d] = f2bf(acc[mi][ni][rr]);
                }
        }
    }
}

// ---------------- K5: Weff = Wc @ wq_q^T (C^T: M=c, N=o), BK=64 swizzled ------------
__global__ __launch_bounds__(256) void k_chain(const unsigned short* __restrict__ Wc,
                                               const unsigned short* __restrict__ wqT,
                                               unsigned short* __restrict__ Weff) {
    __shared__ __align__(16) unsigned short As[128 * 64];   // c-rows (wqT)
    __shared__ __align__(16) unsigned short Bs[128 * 64];   // o-rows (Wc)
    const int t = threadIdx.x;
    const int c0 = blockIdx.x * 128, o0 = blockIdx.y * 128, bz = blockIdx.z;
    const int lane = t & 63, wv = t >> 6, quad = lane >> 4, l15 = lane & 15;
    const int wmC = (wv & 1) * 64, wnO = (wv >> 1) * 64;

    const int srow8 = lane >> 3, sslot = lane & 7;
    const int scol = ((sslot - srow8) & 7) * 8;
    const int sw0 = ((quad + l15) & 7) * 8;

    const unsigned short* Ag = wqT + (size_t)(c0 + wv * 32 + srow8) * HID + scol;
    const unsigned short* Bg = Wc + ((size_t)bz * 256 + o0 + wv * 32 + srow8) * HID + scol;
    unsigned short* Al = As + wv * 32 * 64;
    unsigned short* Bl = Bs + wv * 32 * 64;

    v4f acc[4][4];
    #pragma unroll
    for (int i = 0; i < 4; i++)
        #pragma unroll
        for (int j = 0; j < 4; j++) acc[i][j] = (v4f)0.f;

    for (int kk = 0; kk < HID; kk += 64) {
        #pragma unroll
        for (int cc = 0; cc < 4; cc++) {
            gld_lds16(Ag + (size_t)(cc * 8) * HID + kk, Al + cc * 8 * 64);
            gld_lds16(Bg + (size_t)(cc * 8) * HID + kk, Bl + cc * 8 * 64);
        }
        __syncthreads();
        #pragma unroll
        for (int h = 0; h < 2; h++) {
            const int sw = sw0 ^ (h * 32);
            v8s af[4], bfr[4];
            #pragma unroll
            for (int mi = 0; mi < 4; mi++) {
                union { v8s v; uint4 u; } rr;
                rr.u = *(const uint4*)(&As[(wmC + mi * 16 + l15) * 64 + sw]);
                af[mi] = rr.v;
            }
            #pragma unroll
            for (int ni = 0; ni < 4; ni++) {
                union { v8s v; uint4 u; } rr;
                rr.u = *(const uint4*)(&Bs[(wnO + ni * 16 + l15) * 64 + sw]);
                bfr[ni] = rr.v;
            }
            #pragma unroll
            for (int mi = 0; mi < 4; mi++)
                #pragma unroll
                for (int ni = 0; ni < 4; ni++)
                    acc[mi][ni] = __builtin_amdgcn_mfma_f32_16x16x32_bf16(af[mi], bfr[ni], acc[mi][ni], 0, 0, 0);
        }
        __syncthreads();
    }
    #pragma unroll
    for (int ni = 0; ni < 4; ni++) {
        const int o = o0 + wnO + ni * 16 + l15;
        #pragma unroll
        for (int mi = 0; mi < 4; mi++) {
            const int c = c0 + wmC + mi * 16 + quad * 4;
            union { unsigned short s[4]; uint2 u; } p;
            #pragma unroll
            for (int rr = 0; rr < 4; rr++) p.s[rr] = f2bf(acc[mi][ni][rr]);
            *(uint2*)(Weff + ((size_t)bz * 256 + o) * 256 + c) = p.u;
        }
    }
}

// ---------------- K6: y = Weff @ x + b_out (C^T: M=n, N=o), BK=64 swizzled ----------
__global__ __launch_bounds__(256) void k_y(const unsigned short* __restrict__ Weff,
                                           const unsigned short* __restrict__ xT,
                                           const float* __restrict__ b_out,
                                           float* __restrict__ y) {
    __shared__ __align__(16) unsigned short As[128 * 64];   // n-rows (xT)
    __shared__ __align__(16) unsigned short Bs[128 * 64];   // o-rows (Weff)
    const int t = threadIdx.x;
    const int o0 = blockIdx.x * 128;
    const int n0 = blockIdx.y * 128;
    const int bz = blockIdx.z;
    const int lane = t & 63, wv = t >> 6, quad = lane >> 4, l15 = lane & 15;
    const int wmN = (wv & 1) * 64, wnO = (wv >> 1) * 64;

    const int srow8 = lane >> 3, sslot = lane & 7;
    const int scol = ((sslot - srow8) & 7) * 8;
    const int sw0 = ((quad + l15) & 7) * 8;

    const unsigned short* Ag = xT + ((size_t)bz * NSP + n0 + wv * 32 + srow8) * CIN + scol;
    const unsigned short* Bg = Weff + ((size_t)bz * 256 + o0 + wv * 32 + srow8) * CIN + scol;
    unsigned short* Al = As + wv * 32 * 64;
    unsigned short* Bl = Bs + wv * 32 * 64;

    v4f acc[4][4];
    #pragma unroll
    for (int i = 0; i < 4; i++)
        #pragma unroll
        for (int j = 0; j < 4; j++) acc[i][j] = (v4f)0.f;

    for (int kk = 0; kk < CIN; kk += 64) {
        #pragma unroll
        for (int cc = 0; cc < 4; cc++) {
            gld_lds16(Ag + (size_t)(cc * 8) * CIN + kk, Al + cc * 8 * 64);
            gld_lds16(Bg + (size_t)(cc * 8) * CIN + kk, Bl + cc * 8 * 64);
        }
        __syncthreads();
        #pragma unroll
        for (int h = 0; h < 2; h++) {
            const int sw = sw0 ^ (h * 32);
            v8s af[4], bfr[4];
            #pragma unroll
            for (int mi = 0; mi < 4; mi++) {
                union { v8s v; uint4 u; } rr;
                rr.u = *(const uint4*)(&As[(wmN + mi * 16 + l15) * 64 + sw]);
                af[mi] = rr.v;
            }
            #pragma unroll
            for (int ni = 0; ni < 4; ni++) {
                union { v8s v; uint4 u; } rr;
                rr.u = *(const uint4*)(&Bs[(wnO + ni * 16 + l15) * 64 + sw]);
                bfr[ni] = rr.v;
            }
            #pragma unroll
            for (int mi = 0; mi < 4; mi++)
                #pragma unroll
                for (int ni = 0; ni < 4; ni++)
                    acc[mi][ni] = __builtin_amdgcn_mfma_f32_16x16x32_bf16(af[mi], bfr[ni], acc[mi][ni], 0, 0, 0);
        }
        __syncthreads();
    }
    #pragma unroll
    for (int ni = 0; ni < 4; ni++) {
        const int o = o0 + wnO + ni * 16 + l15;
        const float bias = b_out[o];
        #pragma unroll
        for (int mi = 0; mi < 4; mi++) {
            const int n = n0 + wmN + mi * 16 + quad * 4;
            v4f v = acc[mi][ni];
            v[0] += bias; v[1] += bias; v[2] += bias; v[3] += bias;
            *(v4f*)(y + ((size_t)bz * 256 + o) * NSP + n) = v;
        }
    }
}

extern "C" void kernel_launch(void* const* d_in, const int* in_sizes, int n_in,
                              void* d_out, int out_size, void* d_ws, size_t ws_size,
                              hipStream_t stream) {
    (void)in_sizes; (void)n_in; (void)out_size; (void)ws_size;
    const float* x     = (const float*)d_in[0];
    const float* w_qkv = (const float*)d_in[1];
    const float* w_out = (const float*)d_in[2];
    const float* b_out = (const float*)d_in[3];
    float* y = (float*)d_out;
    char* ws = (char*)d_ws;

    unsigned short* xT   = (unsigned short*)(ws);                 //  33,554,432 B
    unsigned short* xbf  = (unsigned short*)(ws + 33554432);      //  33,554,432 B
    unsigned short* expk = (unsigned short*)(ws + 67108864);      //  67,108,864 B
    float*          Sp   = (float*)(ws + 134217728);              //  33,554,432 B
    float*          zacc = (float*)(ws + 167772160);              //      32,768 B
    unsigned short* Sred = (unsigned short*)(ws + 167804928);     //   4,194,304 B
    unsigned short* Wc   = (unsigned short*)(ws + 171999232);     //   4,194,304 B
    unsigned short* Weff = (unsigned short*)(ws + 176193536);     //   2,097,152 B
    unsigned short* wbf  = (unsigned short*)(ws + 178290688);     //     786,432 B
    unsigned short* wqT  = (unsigned short*)(ws + 179077120);     //     524,288 B

    k_prep <<<dim3(4352),       256, 0, stream>>>(x, w_qkv, xbf, xT, wbf, wqT, zacc);
    k_k    <<<dim3(2048),       256, 0, stream>>>(wbf, xT, expk, zacc);
    k_S    <<<dim3(512),        256, 0, stream>>>(expk, xbf, Sp);
    k_sred <<<dim3(2048),       256, 0, stream>>>(Sp, Sred);
    k_redwc<<<dim3(64),         256, 0, stream>>>(Sred, zacc, wbf, w_out, Wc);
    k_chain<<<dim3(2, 2, 16),   256, 0, stream>>>(Wc, wqT, Weff);
    k_y    <<<dim3(2, 32, 16),  256, 0, stream>>>(Weff, xT, b_out, y);
}